// Round 17
// baseline (104.562 us; speedup 1.0000x reference)
//
#include <hip/hip_runtime.h>

typedef int   int4v  __attribute__((ext_vector_type(4)));
typedef char  char8v __attribute__((ext_vector_type(8)));

#define NROWS 8192
#define DIM 512
#define ROWB 512           // DIM * 1 byte (i8)
#define NT 4               // K-steps of BK=128 per col-tile
#define SWEEP 8            // col-tiles of 64 per block

#define AS1(p) ((const __attribute__((address_space(1))) void*)(p))
#define AS3(p) ((__attribute__((address_space(3))) void*)(p))

#if __has_builtin(__builtin_amdgcn_exp2f)
#define EXP2(x) __builtin_amdgcn_exp2f(x)
#else
#define EXP2(x) exp2f(x)
#endif

// ---------------------------------------------------------------------------
// Kernel 1: wave-per-row normalize + i8 quantize + diag + rowsum zero.
// (identical to R7/R13 — proven)
// ---------------------------------------------------------------------------
__global__ __launch_bounds__(256) void prep_kernel(
    const float* __restrict__ v, const float* __restrict__ u,
    char* __restrict__ vq, char* __restrict__ uq,
    float* __restrict__ sa, float* __restrict__ sb,
    float* __restrict__ diag, float* __restrict__ rowsum)
{
    const int row  = blockIdx.x * 4 + (threadIdx.x >> 6);
    const int lane = threadIdx.x & 63;
    const float4* vr = reinterpret_cast<const float4*>(v + (size_t)row * DIM);
    const float4* ur = reinterpret_cast<const float4*>(u + (size_t)row * DIM);
    const float4 a0 = vr[lane * 2], a1 = vr[lane * 2 + 1];
    const float4 b0 = ur[lane * 2], b1 = ur[lane * 2 + 1];
    float av[8] = {a0.x, a0.y, a0.z, a0.w, a1.x, a1.y, a1.z, a1.w};
    float bv[8] = {b0.x, b0.y, b0.z, b0.w, b1.x, b1.y, b1.z, b1.w};
    float sv = 0.f, su = 0.f, sd = 0.f, mv = 0.f, mu = 0.f;
#pragma unroll
    for (int i = 0; i < 8; ++i) {
        sv += av[i] * av[i];
        su += bv[i] * bv[i];
        sd += av[i] * bv[i];
        mv = fmaxf(mv, fabsf(av[i]));
        mu = fmaxf(mu, fabsf(bv[i]));
    }
#pragma unroll
    for (int m = 32; m; m >>= 1) {
        sv += __shfl_xor(sv, m);
        su += __shfl_xor(su, m);
        sd += __shfl_xor(sd, m);
        mv = fmaxf(mv, __shfl_xor(mv, m));
        mu = fmaxf(mu, __shfl_xor(mu, m));
    }
    const float rv = 1.0f / fmaxf(sqrtf(sv), 1e-8f);
    const float ru = 1.0f / fmaxf(sqrtf(su), 1e-8f);
    const float qv = 127.0f / fmaxf(mv, 1e-20f);
    const float qu = 127.0f / fmaxf(mu, 1e-20f);
    char8v cv, cu;
#pragma unroll
    for (int i = 0; i < 8; ++i) {
        cv[i] = (char)__float2int_rn(av[i] * qv);
        cu[i] = (char)__float2int_rn(bv[i] * qu);
    }
    reinterpret_cast<char8v*>(vq + (size_t)row * DIM)[lane] = cv;
    reinterpret_cast<char8v*>(uq + (size_t)row * DIM)[lane] = cu;
    if (lane == 0) {
        sa[row] = mv * rv / 127.0f;
        sb[row] = mu * ru / 127.0f;
        diag[row] = sd * rv * ru;
        rowsum[row] = 0.0f;
    }
}

// ---------------------------------------------------------------------------
// Kernel 2: R17 = R13 byte-for-byte with the m-dimension doubled.
// 64 rows/wave halves the LDS-read invariant (1 GB -> 512 MB) — the one
// lever left (R13 analysis). Built ONLY from R13-proven parts:
//   - ring 4 x 8 KB, 2-gload stage, counted vmcnt(2), zero-drain barriers
//   - the R5/R7/R13 XOR swizzle byte-for-byte (0 conflicts measured)
// Register budget (R14's spill causes removed: no 8-gload stage, no new
// swizzle arithmetic, no ga/rs arrays): Areg 128 + acc 64 + Bf 8 + misc
// ~25 ~= 225-240 < 256 cap at (256,2). Per step: 32 MFMA : 8 ds_read_b128
// (MFMA-dominant for the first time). rows/block = 256 also halves B
// staging traffic. Block = 4 waves x 64 rows; sweeps 8 col-tiles of 64.
// Grid 32 x 16 = 512 blocks (2/CU, 2 waves/SIMD).
// SPILL TRIPWIRE: WRITE_SIZE >> 4 KB => revert to R13, declare ceiling.
// ---------------------------------------------------------------------------
__global__ __launch_bounds__(256, 2) void simsum_kernel(
    const char* __restrict__ A, const char* __restrict__ Bq,
    const float* __restrict__ sa, const float* __restrict__ sb,
    float* __restrict__ rowsum)
{
    __shared__ __align__(16) char ldsB[4][8192];   // ring: 4 x (64 cols x 128 B)
    const int tid  = threadIdx.x;
    const int wave = tid >> 6;
    const int lane = tid & 63;
    const int ln15 = lane & 15;
    const int lhi  = lane >> 4;
    const int swz  = (ln15 & 7) << 4;          // read-side XOR (= col&7 <<4)

    const int brow = blockIdx.x;               // 0..31 -> 256 rows each
    const int bgrp = blockIdx.y;               // 0..15 -> 8 col-tiles of 64
    const int growA = brow * 256 + wave * 64;  // this wave's 64 rows
    const int gcol0 = bgrp * (SWEEP * 64);     // this block's 512 cols

    // ---- A into registers: [t][kk][m], 32 x int4v = 128 VGPR ----
    int4v Areg[NT][2][4];
#pragma unroll
    for (int t = 0; t < NT; ++t)
#pragma unroll
        for (int kk = 0; kk < 2; ++kk)
#pragma unroll
            for (int m = 0; m < 4; ++m) {
                const int r = growA + m * 16 + ln15;
                Areg[t][kk][m] = *reinterpret_cast<const int4v*>(
                    A + (size_t)r * ROWB + t * 128 + kk * 64 + lhi * 16);
            }

    // staging: 2 gloads/thread cover one 8 KB col-tile-K-step; linear LDS
    // dest, source k-chunk pre-swizzled (G21 pairing, 0-conflict R5/R7/R13).
    const int r0   = tid >> 3;
    const int sl16 = (((tid & 7) ^ ((tid >> 3) & 7)) << 4);

    auto stageB = [&](int bi, int gs) {       // gs = global step 0..31
        const int ct = gs >> 2;               // col-tile 0..7
        const int kt = gs & 3;                // K-step 0..3
#pragma unroll
        for (int q = 0; q < 2; ++q) {
            const int col = gcol0 + ct * 64 + q * 32 + r0;
            __builtin_amdgcn_global_load_lds(
                AS1(Bq + (size_t)col * ROWB + kt * 128 + sl16),
                AS3(&ldsB[bi][q * 4096 + tid * 16]), 16, 0, 0);
        }
    };

    // ---- prologue: depth-2 ----
    stageB(0, 0);
    stageB(1, 1);
    asm volatile("s_waitcnt vmcnt(2)" ::: "memory");   // step 0 landed
    asm volatile("s_barrier" ::: "memory");

    const float C2 = 2.885390081777927f;   // 2 * log2(e)

    for (int s = 0; s < SWEEP; ++s) {
        int4v acc[4][4];
#pragma unroll
        for (int m = 0; m < 4; ++m)
#pragma unroll
            for (int n = 0; n < 4; ++n)
                acc[m][n] = (int4v){0, 0, 0, 0};

#pragma unroll
        for (int tt = 0; tt < NT; ++tt) {
            const int g = s * 4 + tt;
            if (g + 2 < 32) stageB((tt + 2) & 3, g + 2);
#pragma unroll
            for (int kk = 0; kk < 2; ++kk) {
                int4v Bf[4];
#pragma unroll
                for (int n = 0; n < 4; ++n) {
                    const int c = n * 16 + ln15;
                    Bf[n] = *reinterpret_cast<const int4v*>(
                        &ldsB[tt & 3][c * 128 + ((kk * 64 + lhi * 16) ^ swz)]);
                }
#pragma unroll
                for (int m = 0; m < 4; ++m)
#pragma unroll
                    for (int n = 0; n < 4; ++n)
                        acc[m][n] = __builtin_amdgcn_mfma_i32_16x16x64_i8(
                            Areg[tt][kk][m], Bf[n], acc[m][n], 0, 0, 0);
            }
            // counted wait: g+1's 2 loads drained, g+2's stay in flight
            if (g < 30)       asm volatile("s_waitcnt vmcnt(2)" ::: "memory");
            else if (g == 30) asm volatile("s_waitcnt vmcnt(0)" ::: "memory");
            if (g < 31)       asm volatile("s_barrier" ::: "memory");
        }

        // epilogue for this 64-col tile (sa loaded inline — no ga array)
        float sbv[4];
#pragma unroll
        for (int n = 0; n < 4; ++n)
            sbv[n] = sb[gcol0 + s * 64 + n * 16 + ln15];
#pragma unroll
        for (int m = 0; m < 4; ++m)
#pragma unroll
            for (int rr = 0; rr < 4; ++rr) {
                const int grow = growA + m * 16 + lhi * 4 + rr;
                const float g2 = sa[grow] * C2;
                float sum = 0.f;
#pragma unroll
                for (int n = 0; n < 4; ++n)
                    sum += EXP2((float)acc[m][n][rr] * g2 * sbv[n]);
                sum += __shfl_xor(sum, 1);
                sum += __shfl_xor(sum, 2);
                sum += __shfl_xor(sum, 4);
                sum += __shfl_xor(sum, 8);
                if (ln15 == 0)
                    atomicAdd(&rowsum[grow], sum);
            }
    }
}

// ---------------------------------------------------------------------------
// Kernel 3: loss_i = log(exp(2*diag_i) + rowsum_i) - 2*diag_i
// ---------------------------------------------------------------------------
__global__ __launch_bounds__(256) void loss_kernel(
    const float* __restrict__ diag, const float* __restrict__ rowsum,
    float* __restrict__ out)
{
    const int i = blockIdx.x * 256 + threadIdx.x;
    const float d2 = diag[i] * 2.0f;
    out[i] = logf(expf(d2) + rowsum[i]) - d2;
}

extern "C" void kernel_launch(void* const* d_in, const int* in_sizes, int n_in,
                              void* d_out, int out_size, void* d_ws, size_t ws_size,
                              hipStream_t stream) {
    const float* v = (const float*)d_in[0];
    const float* u = (const float*)d_in[1];
    float* out = (float*)d_out;
    char* ws = (char*)d_ws;
    char*  vq     = ws;                                   // 4 MiB
    char*  uq     = ws + (size_t)4194304;                 // 4 MiB
    float* sa     = (float*)(ws + (size_t)8388608);       // 32 KiB
    float* sb     = (float*)(ws + (size_t)8388608 + 32768);
    float* diag   = (float*)(ws + (size_t)8388608 + 65536);
    float* rowsum = (float*)(ws + (size_t)8388608 + 98304);

    prep_kernel<<<NROWS / 4, 256, 0, stream>>>(v, u, vq, uq, sa, sb, diag, rowsum);
    dim3 grid(32, 16);
    simsum_kernel<<<grid, 256, 0, stream>>>(vq, uq, sa, sb, rowsum);
    loss_kernel<<<NROWS / 256, 256, 0, stream>>>(diag, rowsum, out);
}

// Round 18
// 51.784 us; speedup vs baseline: 2.0192x; 2.0192x over previous
//
#include <hip/hip_runtime.h>

typedef int   int4v  __attribute__((ext_vector_type(4)));
typedef char  char8v __attribute__((ext_vector_type(8)));

#define NROWS 8192
#define DIM 512
#define ROWB 512           // DIM * 1 byte (i8)
#define NT 4               // K-steps of BK=128 per col-tile
#define SWEEP 8            // col-tiles of 128 per block (R7 geometry)

#define AS1(p) ((const __attribute__((address_space(1))) void*)(p))
#define AS3(p) ((__attribute__((address_space(3))) void*)(p))

#if __has_builtin(__builtin_amdgcn_exp2f)
#define EXP2(x) __builtin_amdgcn_exp2f(x)
#else
#define EXP2(x) exp2f(x)
#endif

// ---------------------------------------------------------------------------
// Kernel 1: wave-per-row normalize + i8 quantize + diag + rowsum zero.
// (proven R7-R17)
// ---------------------------------------------------------------------------
__global__ __launch_bounds__(256) void prep_kernel(
    const float* __restrict__ v, const float* __restrict__ u,
    char* __restrict__ vq, char* __restrict__ uq,
    float* __restrict__ sa, float* __restrict__ sb,
    float* __restrict__ diag, float* __restrict__ rowsum)
{
    const int row  = blockIdx.x * 4 + (threadIdx.x >> 6);
    const int lane = threadIdx.x & 63;
    const float4* vr = reinterpret_cast<const float4*>(v + (size_t)row * DIM);
    const float4* ur = reinterpret_cast<const float4*>(u + (size_t)row * DIM);
    const float4 a0 = vr[lane * 2], a1 = vr[lane * 2 + 1];
    const float4 b0 = ur[lane * 2], b1 = ur[lane * 2 + 1];
    float av[8] = {a0.x, a0.y, a0.z, a0.w, a1.x, a1.y, a1.z, a1.w};
    float bv[8] = {b0.x, b0.y, b0.z, b0.w, b1.x, b1.y, b1.z, b1.w};
    float sv = 0.f, su = 0.f, sd = 0.f, mv = 0.f, mu = 0.f;
#pragma unroll
    for (int i = 0; i < 8; ++i) {
        sv += av[i] * av[i];
        su += bv[i] * bv[i];
        sd += av[i] * bv[i];
        mv = fmaxf(mv, fabsf(av[i]));
        mu = fmaxf(mu, fabsf(bv[i]));
    }
#pragma unroll
    for (int m = 32; m; m >>= 1) {
        sv += __shfl_xor(sv, m);
        su += __shfl_xor(su, m);
        sd += __shfl_xor(sd, m);
        mv = fmaxf(mv, __shfl_xor(mv, m));
        mu = fmaxf(mu, __shfl_xor(mu, m));
    }
    const float rv = 1.0f / fmaxf(sqrtf(sv), 1e-8f);
    const float ru = 1.0f / fmaxf(sqrtf(su), 1e-8f);
    const float qv = 127.0f / fmaxf(mv, 1e-20f);
    const float qu = 127.0f / fmaxf(mu, 1e-20f);
    char8v cv, cu;
#pragma unroll
    for (int i = 0; i < 8; ++i) {
        cv[i] = (char)__float2int_rn(av[i] * qv);
        cu[i] = (char)__float2int_rn(bv[i] * qu);
    }
    reinterpret_cast<char8v*>(vq + (size_t)row * DIM)[lane] = cv;
    reinterpret_cast<char8v*>(uq + (size_t)row * DIM)[lane] = cu;
    if (lane == 0) {
        sa[row] = mv * rv / 127.0f;
        sb[row] = mu * ru / 127.0f;
        diag[row] = sd * rv * ru;
        rowsum[row] = 0.0f;
    }
}

// ---------------------------------------------------------------------------
// Kernel 2: R13 verbatim — best measured configuration (41.6us simsum).
// A-stationary (64 VGPR), 32 rows/wave x 128 cols/step, ring-4 x 16 KB LDS,
// depth-2 prefetch, counted vmcnt(4) (never 0 until tail), raw s_barrier
// (no drain), proven XOR swizzle (0 conflicts), fused exp2 rowsum epilogue.
// 13 structural variants (R2-R4 deep-phase, R8/R15 occupancy-cap, R10/R14/
// R17 64-row, R11 small-tile, R12 barrier-free, R16 wave-private) all
// regressed — this is the family's practical floor at 2 waves/SIMD.
// ---------------------------------------------------------------------------
__global__ __launch_bounds__(256, 2) void simsum_kernel(
    const char* __restrict__ A, const char* __restrict__ Bq,
    const float* __restrict__ sa, const float* __restrict__ sb,
    float* __restrict__ rowsum)
{
    __shared__ __align__(16) char ldsB[4][16384];  // ring: 4 x (128 cols x 128 B)
    const int tid  = threadIdx.x;
    const int wave = tid >> 6;
    const int lane = tid & 63;
    const int ln15 = lane & 15;
    const int lhi  = lane >> 4;
    const int swz  = (ln15 & 7) << 4;          // read-side XOR (= col&7 <<4)

    const int brow = blockIdx.x;               // 0..63 -> 128 rows each
    const int bgrp = blockIdx.y;               // 0..7  -> 8 col-tiles of 128
    const int growA = brow * 128 + wave * 32;  // this wave's 32 rows
    const int gcol0 = bgrp * (SWEEP * 128);    // this block's 1024 cols

    const char* gA = A;
    const char* gB = Bq;

    // ---- A into registers: [t][kk][m], 16 x int4v = 64 VGPR ----
    int4v Areg[NT][2][2];
#pragma unroll
    for (int t = 0; t < NT; ++t)
#pragma unroll
        for (int kk = 0; kk < 2; ++kk)
#pragma unroll
            for (int m = 0; m < 2; ++m) {
                const int r = growA + m * 16 + ln15;
                Areg[t][kk][m] = *reinterpret_cast<const int4v*>(
                    gA + (size_t)r * ROWB + t * 128 + kk * 64 + lhi * 16);
            }

    // per-row dequant scale (x 2*log2e) for this thread's 8 rows
    const float C2 = 2.885390081777927f;   // 2 * log2(e)
    float ga[2][4];
#pragma unroll
    for (int m = 0; m < 2; ++m)
#pragma unroll
        for (int rr = 0; rr < 4; ++rr)
            ga[m][rr] = sa[growA + m * 16 + lhi * 4 + rr] * C2;

    float rs[2][4];
#pragma unroll
    for (int m = 0; m < 2; ++m)
#pragma unroll
        for (int rr = 0; rr < 4; ++rr)
            rs[m][rr] = 0.f;

    // staging: 4 gloads/thread cover one 16 KB col-tile-K-step; linear LDS
    // dest, source k-chunk pre-swizzled (G21 both-sides pairing, 0-conflict).
    const int r0   = tid >> 3;
    const int sl16 = (((tid & 7) ^ ((tid >> 3) & 7)) << 4);

    auto stageB = [&](int bi, int gs) {       // gs = global step 0..31
        const int ct = gs >> 2;               // col-tile 0..7
        const int kt = gs & 3;                // K-step 0..3
#pragma unroll
        for (int q = 0; q < 4; ++q) {
            const int col = gcol0 + ct * 128 + q * 32 + r0;
            __builtin_amdgcn_global_load_lds(
                AS1(gB + (size_t)col * ROWB + kt * 128 + sl16),
                AS3(&ldsB[bi][q * 4096 + tid * 16]), 16, 0, 0);
        }
    };

    // ---- prologue: depth-2 ----
    stageB(0, 0);
    stageB(1, 1);
    asm volatile("s_waitcnt vmcnt(4)" ::: "memory");   // step 0 landed
    asm volatile("s_barrier" ::: "memory");

    for (int s = 0; s < SWEEP; ++s) {
        int4v acc[2][8];
#pragma unroll
        for (int m = 0; m < 2; ++m)
#pragma unroll
            for (int n = 0; n < 8; ++n)
                acc[m][n] = (int4v){0, 0, 0, 0};

#pragma unroll
        for (int tt = 0; tt < NT; ++tt) {
            const int g = s * 4 + tt;
            if (g + 2 < 32) stageB((tt + 2) & 3, g + 2);
#pragma unroll
            for (int kk = 0; kk < 2; ++kk) {
                int4v Bf[8];
#pragma unroll
                for (int n = 0; n < 8; ++n) {
                    const int c = n * 16 + ln15;
                    Bf[n] = *reinterpret_cast<const int4v*>(
                        &ldsB[tt & 3][c * 128 + ((kk * 64 + lhi * 16) ^ swz)]);
                }
#pragma unroll
                for (int m = 0; m < 2; ++m)
#pragma unroll
                    for (int n = 0; n < 8; ++n)
                        acc[m][n] = __builtin_amdgcn_mfma_i32_16x16x64_i8(
                            Areg[tt][kk][m], Bf[n], acc[m][n], 0, 0, 0);
            }
            // counted wait: g+1's 4 loads drained, g+2's stay in flight
            if (g < 30)       asm volatile("s_waitcnt vmcnt(4)" ::: "memory");
            else if (g == 30) asm volatile("s_waitcnt vmcnt(0)" ::: "memory");
            if (g < 31)       asm volatile("s_barrier" ::: "memory");
        }

        // fused epilogue for this 128-col tile: lane-local partial row sums
        float sbv[8];
#pragma unroll
        for (int n = 0; n < 8; ++n)
            sbv[n] = sb[gcol0 + s * 128 + n * 16 + ln15];
#pragma unroll
        for (int m = 0; m < 2; ++m)
#pragma unroll
            for (int rr = 0; rr < 4; ++rr) {
                const float g2 = ga[m][rr];
#pragma unroll
                for (int n = 0; n < 8; ++n)
                    rs[m][rr] += EXP2((float)acc[m][n][rr] * g2 * sbv[n]);
            }
    }

    // final cross-lane reduce (cols live across ln15) + one atomic per row
#pragma unroll
    for (int m = 0; m < 2; ++m)
#pragma unroll
        for (int rr = 0; rr < 4; ++rr) {
            float s = rs[m][rr];
            s += __shfl_xor(s, 1);
            s += __shfl_xor(s, 2);
            s += __shfl_xor(s, 4);
            s += __shfl_xor(s, 8);
            if (ln15 == 0)
                atomicAdd(&rowsum[growA + m * 16 + lhi * 4 + rr], s);
        }
}

// ---------------------------------------------------------------------------
// Kernel 3: loss_i = log(exp(2*diag_i) + rowsum_i) - 2*diag_i
// ---------------------------------------------------------------------------
__global__ __launch_bounds__(256) void loss_kernel(
    const float* __restrict__ diag, const float* __restrict__ rowsum,
    float* __restrict__ out)
{
    const int i = blockIdx.x * 256 + threadIdx.x;
    const float d2 = diag[i] * 2.0f;
    out[i] = logf(expf(d2) + rowsum[i]) - d2;
}

extern "C" void kernel_launch(void* const* d_in, const int* in_sizes, int n_in,
                              void* d_out, int out_size, void* d_ws, size_t ws_size,
                              hipStream_t stream) {
    const float* v = (const float*)d_in[0];
    const float* u = (const float*)d_in[1];
    float* out = (float*)d_out;
    char* ws = (char*)d_ws;
    char*  vq     = ws;                                   // 4 MiB
    char*  uq     = ws + (size_t)4194304;                 // 4 MiB
    float* sa     = (float*)(ws + (size_t)8388608);       // 32 KiB
    float* sb     = (float*)(ws + (size_t)8388608 + 32768);
    float* diag   = (float*)(ws + (size_t)8388608 + 65536);
    float* rowsum = (float*)(ws + (size_t)8388608 + 98304);

    prep_kernel<<<NROWS / 4, 256, 0, stream>>>(v, u, vq, uq, sa, sb, diag, rowsum);
    dim3 grid(64, 8);
    simsum_kernel<<<grid, 256, 0, stream>>>(vq, uq, sa, sb, rowsum);
    loss_kernel<<<NROWS / 256, 256, 0, stream>>>(diag, rowsum, out);
}